// Round 10
// baseline (1059.848 us; speedup 1.0000x reference)
//
#include <hip/hip_runtime.h>
#include <stdint.h>

// ---------------------------------------------------------------------------
// Qwen3.5-MoE gated SDPA attention block, MI355X (gfx950)
// R10: instrumented bisect. Authoritative path = verified round-4 pipeline
// (passed, 831us). R5 swapped-operand attn runs as a PROBE whose output is
// overwritten by the verified attn kernel -> counters without correctness
// exposure. B=2 S=2048 HID=2048 H=16 KV=4 D=128
// ---------------------------------------------------------------------------

using bf16 = unsigned short;                                  // raw bf16 bits
typedef __attribute__((ext_vector_type(8)))  short bf16x8;    // MFMA A/B frag
typedef __attribute__((ext_vector_type(4)))  float f32x4;     // 16x16 C/D
typedef __attribute__((ext_vector_type(16))) float f32x16;    // 32x32 C/D

__device__ __forceinline__ unsigned short f2bf(float x) {
  unsigned int u = __float_as_uint(x);
  unsigned int r = u + 0x7fffu + ((u >> 16) & 1u);            // RNE
  return (unsigned short)(r >> 16);
}

__device__ __forceinline__ unsigned int pk2(float a, float b) {
  return (unsigned int)f2bf(a) | ((unsigned int)f2bf(b) << 16);
}

__device__ __forceinline__ void async_copy16(const void* g, void* l) {
  __builtin_amdgcn_global_load_lds(
      (const __attribute__((address_space(1))) void*)g,
      (__attribute__((address_space(3))) void*)l, 16, 0, 0);
}

// ---------------------------------------------------------------------------
// fp32 -> bf16 convert, 4 elems/thread, exact grid
// ---------------------------------------------------------------------------
__global__ void f2b_kernel(const float* __restrict__ in, bf16* __restrict__ out) {
  int i = (blockIdx.x * 256 + threadIdx.x) * 4;
  float4 v = *(const float4*)(in + i);
  ushort4 o;
  o.x = f2bf(v.x); o.y = f2bf(v.y); o.z = f2bf(v.z); o.w = f2bf(v.w);
  *(ushort4*)(out + i) = o;
}

// ---------------------------------------------------------------------------
// C[m][n] = sum_k A[m][k] * B[n][k]   (A MxK bf16, B NxK bf16, C fp32)
// 128x128 tile, BK=32, 4 waves (2x2), m97 structure + XCD swizzle  [verified]
// ---------------------------------------------------------------------------
__global__ __launch_bounds__(256) void gemm_bt(const bf16* __restrict__ A,
                                               const bf16* __restrict__ B,
                                               float* __restrict__ C,
                                               int M, int N, int K) {
  __shared__ __align__(16) bf16 As[128 * 32];
  __shared__ __align__(16) bf16 Bs[128 * 32];
  const int tid = threadIdx.x;
  const int w = tid >> 6, lane = tid & 63;
  const int wr = w >> 1, wc = w & 1;
  const int li = lane & 15, hi = lane >> 4;

  const int nbx = gridDim.x, nwg = nbx * gridDim.y;
  const int orig = blockIdx.y * nbx + blockIdx.x;
  const int tileid = (orig & 7) * (nwg >> 3) + (orig >> 3);
  const int bm = (tileid / nbx) * 128, bn = (tileid % nbx) * 128;

  f32x4 acc[4][4];
#pragma unroll
  for (int m = 0; m < 4; m++)
#pragma unroll
    for (int n = 0; n < 4; n++) acc[m][n] = (f32x4){0.f, 0.f, 0.f, 0.f};

  const int c0 = tid, c1 = tid + 256;
  const bf16* Ab = A + (long long)bm * K;
  const bf16* Bb = B + (long long)bn * K;

  for (int k0 = 0; k0 < K; k0 += 32) {
    async_copy16(Ab + (c0 >> 2) * K + k0 + (c0 & 3) * 8, (char*)As + c0 * 16);
    async_copy16(Ab + (c1 >> 2) * K + k0 + (c1 & 3) * 8, (char*)As + c1 * 16);
    async_copy16(Bb + (c0 >> 2) * K + k0 + (c0 & 3) * 8, (char*)Bs + c0 * 16);
    async_copy16(Bb + (c1 >> 2) * K + k0 + (c1 & 3) * 8, (char*)Bs + c1 * 16);
    __syncthreads();

    bf16x8 af[4], bfv[4];
#pragma unroll
    for (int m = 0; m < 4; m++)
      af[m] = *(const bf16x8*)(As + (wr * 64 + m * 16 + li) * 32 + hi * 8);
#pragma unroll
    for (int n = 0; n < 4; n++)
      bfv[n] = *(const bf16x8*)(Bs + (wc * 64 + n * 16 + li) * 32 + hi * 8);
#pragma unroll
    for (int m = 0; m < 4; m++)
#pragma unroll
      for (int n = 0; n < 4; n++)
        acc[m][n] = __builtin_amdgcn_mfma_f32_16x16x32_bf16(af[m], bfv[n],
                                                            acc[m][n], 0, 0, 0);
    __syncthreads();
  }

#pragma unroll
  for (int m = 0; m < 4; m++)
#pragma unroll
    for (int n = 0; n < 4; n++) {
      int row = bm + wr * 64 + m * 16 + hi * 4;
      int col = bn + wc * 64 + n * 16 + li;
#pragma unroll
      for (int r = 0; r < 4; r++) C[(long long)(row + r) * N + col] = acc[m][n][r];
    }
}

// ---------------------------------------------------------------------------
// RMSNorm + RoPE + pack to bf16 (one wave per (token, head-row))  [verified]
// ---------------------------------------------------------------------------
__global__ __launch_bounds__(256) void pack_qk(
    const float* __restrict__ qg_raw, const float* __restrict__ kv_raw,
    const float* __restrict__ cosb, const float* __restrict__ sinb,
    const float* __restrict__ qnw, const float* __restrict__ knw,
    bf16* __restrict__ q_pack, bf16* __restrict__ k_pack) {
  int rowid = blockIdx.x * 4 + (threadIdx.x >> 6);
  int lane = threadIdx.x & 63;
  int token = rowid / 20, r = rowid % 20;
  int b = token >> 11, s = token & 2047;
  const float* src; const float* wn; bf16* dst; float scale;
  if (r < 16) {
    src = qg_raw + (long long)token * 4096 + r * 256;
    wn = qnw;
    dst = q_pack + ((long long)(b * 16 + r) * 2048 + s) * 128;
    scale = 0.08838834764831845f;                      // D^-0.5 folded into q
  } else {
    int kv = r - 16;
    src = kv_raw + (long long)token * 1024 + kv * 128;
    wn = knw;
    dst = k_pack + ((long long)(b * 4 + kv) * 2048 + s) * 128;
    scale = 1.0f;
  }
  float x0 = src[lane], x1 = src[lane + 64];
  float ss = x0 * x0 + x1 * x1;
#pragma unroll
  for (int off = 32; off > 0; off >>= 1) ss += __shfl_xor(ss, off);
  float inv = rsqrtf(ss * (1.0f / 128.0f) + 1e-6f);
  float n0 = x0 * inv * (1.f + wn[lane]);
  float n1 = x1 * inv * (1.f + wn[lane + 64]);
  const float* cp = cosb + (long long)(b * 2048 + s) * 128;
  const float* sp = sinb + (long long)(b * 2048 + s) * 128;
  dst[lane]      = f2bf((n0 * cp[lane]      - n1 * sp[lane])      * scale);
  dst[lane + 64] = f2bf((n1 * cp[lane + 64] + n0 * sp[lane + 64]) * scale);
}

// ---------------------------------------------------------------------------
// V transpose: kv_raw[token][512+c] (fp32) -> vt[b][c][s] (bf16)  [verified]
// ---------------------------------------------------------------------------
__global__ __launch_bounds__(256) void transpose_v(const float* __restrict__ kv_raw,
                                                   bf16* __restrict__ vt) {
  __shared__ float tile[32][33];
  int b = blockIdx.z;
  int c0 = blockIdx.x * 32;
  int s0 = blockIdx.y * 32;
  int tx = threadIdx.x & 31, ty = threadIdx.x >> 5;
#pragma unroll
  for (int i = 0; i < 32; i += 8)
    tile[ty + i][tx] = kv_raw[(long long)(b * 2048 + s0 + ty + i) * 1024 + 512 + c0 + tx];
  __syncthreads();
#pragma unroll
  for (int i = 0; i < 32; i += 8)
    vt[(long long)(b * 512 + c0 + ty + i) * 2048 + s0 + tx] = f2bf(tile[tx][ty + i]);
}

// ---------------------------------------------------------------------------
// PROBE (R5): swapped-operand flash attn, 32x32 MFMA, lane-local softmax.
// Output overwritten by the verified attn_kernel below -> perf counters only.
// ---------------------------------------------------------------------------
__global__ __launch_bounds__(256) void attn_probe(
    const bf16* __restrict__ qp, const bf16* __restrict__ kp,
    const bf16* __restrict__ vt, const float* __restrict__ qg_raw,
    bf16* __restrict__ attn_g) {
  const int w = threadIdx.x >> 6, lane = threadIdx.x & 63;
  const int l31 = lane & 31, hi2 = lane >> 5;
  const int bh = blockIdx.y, b = bh >> 4, h = bh & 15, kv = h >> 2;
  const int qtile = (gridDim.x - 1) - blockIdx.x;       // heavy tiles first
  const int q0w = qtile * 128 + w * 32;
  const int q = q0w + l31;

  const bf16* qb = qp + ((long long)(b * 16 + h) * 2048 + q0w) * 128;
  const bf16* kb = kp + (long long)(b * 4 + kv) * 2048 * 128;
  const bf16* vb = vt + (long long)(b * 4 + kv) * 128 * 2048;

  bf16x8 qf[8];
#pragma unroll
  for (int d = 0; d < 8; d++)
    qf[d] = *(const bf16x8*)(qb + l31 * 128 + d * 16 + hi2 * 8);

  f32x16 O[4];
#pragma unroll
  for (int ct = 0; ct < 4; ct++)
#pragma unroll
    for (int i = 0; i < 16; i++) O[ct][i] = 0.f;

  float mval = -1e30f, lsum = 0.f;
  const int ktmax = q0w >> 5;

  bf16x8 kf[8];
#pragma unroll
  for (int d = 0; d < 8; d++)
    kf[d] = *(const bf16x8*)(kb + l31 * 128 + d * 16 + hi2 * 8);

  for (int kt = 0; kt <= ktmax; kt++) {
    const int k0 = kt * 32;

    f32x16 s;
#pragma unroll
    for (int i = 0; i < 16; i++) s[i] = 0.f;
#pragma unroll
    for (int d = 0; d < 8; d++)
      s = __builtin_amdgcn_mfma_f32_32x32x16_bf16(kf[d], qf[d], s, 0, 0, 0);

    const int k0n = (kt < ktmax) ? (k0 + 32) : k0;
#pragma unroll
    for (int d = 0; d < 8; d++)
      kf[d] = *(const bf16x8*)(kb + (k0n + l31) * 128 + d * 16 + hi2 * 8);

    bf16x8 vf[8];
#pragma unroll
    for (int ct = 0; ct < 4; ct++)
#pragma unroll
      for (int kc = 0; kc < 2; kc++)
        vf[ct * 2 + kc] =
            *(const bf16x8*)(vb + (ct * 32 + l31) * 2048 + k0 + kc * 16 + hi2 * 8);

    if (k0 + 31 > q0w) {
#pragma unroll
      for (int r = 0; r < 16; r++) {
        int kk = k0 + (r & 3) + 8 * (r >> 2) + 4 * hi2;
        if (kk > q) s[r] = -1e30f;
      }
    }

    float pm = s[0];
#pragma unroll
    for (int r = 1; r < 16; r++) pm = fmaxf(pm, s[r]);
    pm = fmaxf(pm, __shfl_xor(pm, 32));

    int keep = __all(pm <= mval + 8.0f);                // T13 defer-max
    float mn = mval, alpha = 1.f;
    if (!keep) {
      mn = fmaxf(mval, pm);
      alpha = __expf(mval - mn);
      mval = mn;
    }
    float sum = 0.f;
#pragma unroll
    for (int r = 0; r < 16; r++) { s[r] = __expf(s[r] - mn); sum += s[r]; }
    sum += __shfl_xor(sum, 32);
    if (keep) {
      lsum += sum;
    } else {
      lsum = lsum * alpha + sum;
#pragma unroll
      for (int ct = 0; ct < 4; ct++)
#pragma unroll
        for (int i = 0; i < 16; i++) O[ct][i] *= alpha;
    }

    bf16x8 pf[2];
#pragma unroll
    for (int kc = 0; kc < 2; kc++) {
      unsigned int wA = pk2(s[8 * kc + 0], s[8 * kc + 1]);
      unsigned int wB = pk2(s[8 * kc + 2], s[8 * kc + 3]);
      unsigned int wC = pk2(s[8 * kc + 4], s[8 * kc + 5]);
      unsigned int wD = pk2(s[8 * kc + 6], s[8 * kc + 7]);
      unsigned int xA = (unsigned int)__shfl_xor((int)wA, 32);
      unsigned int xB = (unsigned int)__shfl_xor((int)wB, 32);
      unsigned int xC = (unsigned int)__shfl_xor((int)wC, 32);
      unsigned int xD = (unsigned int)__shfl_xor((int)wD, 32);
      union { unsigned int u[4]; bf16x8 v; } pu;
      pu.u[0] = hi2 ? xC : wA;
      pu.u[1] = hi2 ? xD : wB;
      pu.u[2] = hi2 ? wC : xA;
      pu.u[3] = hi2 ? wD : xB;
      pf[kc] = pu.v;
    }

#pragma unroll
    for (int ct = 0; ct < 4; ct++) {
      O[ct] = __builtin_amdgcn_mfma_f32_32x32x16_bf16(vf[ct * 2 + 0], pf[0], O[ct], 0, 0, 0);
      O[ct] = __builtin_amdgcn_mfma_f32_32x32x16_bf16(vf[ct * 2 + 1], pf[1], O[ct], 0, 0, 0);
    }
  }

  const float linv = 1.f / lsum;
  const long long tok = (long long)(b * 2048 + q);
#pragma unroll
  for (int ct = 0; ct < 4; ct++)
#pragma unroll
    for (int r = 0; r < 16; r++) {
      int c = ct * 32 + (r & 3) + 8 * (r >> 2) + 4 * hi2;
      float g = qg_raw[tok * 4096 + h * 256 + 128 + c];
      float val = O[ct][r] * linv * (1.f / (1.f + __expf(-g)));
      attn_g[tok * 2048 + h * 128 + c] = f2bf(val);
    }
}

// ---------------------------------------------------------------------------
// AUTHORITATIVE attn (round-4, verified pass): 16x16 MFMA, LDS P round-trip.
// Runs AFTER the probe and overwrites attn_g entirely.
// ---------------------------------------------------------------------------
__global__ __launch_bounds__(256) void attn_kernel(
    const bf16* __restrict__ qp, const bf16* __restrict__ kp,
    const bf16* __restrict__ vt, const float* __restrict__ qg_raw,
    bf16* __restrict__ attn_g) {
  __shared__ __align__(16) bf16 Pl[4][16][32];        // per-wave P transpose
  const int w = threadIdx.x >> 6, lane = threadIdx.x & 63;
  const int li = lane & 15, hi = lane >> 4;
  const int bh = blockIdx.y, b = bh >> 4, h = bh & 15, kv = h >> 2;
  const int q0 = blockIdx.x * 64 + w * 16;
  const bf16* qb = qp + ((long long)(b * 16 + h) * 2048 + q0) * 128;
  const bf16* kb = kp + (long long)(b * 4 + kv) * 2048 * 128;
  const bf16* vb = vt + (long long)(b * 4 + kv) * 128 * 2048;

  bf16x8 qf[4];
#pragma unroll
  for (int kd = 0; kd < 4; kd++)
    qf[kd] = *(const bf16x8*)(qb + li * 128 + kd * 32 + hi * 8);

  f32x4 O[8];
#pragma unroll
  for (int t = 0; t < 8; t++) O[t] = (f32x4){0.f, 0.f, 0.f, 0.f};
  float m[4] = {-1e30f, -1e30f, -1e30f, -1e30f};
  float l[4] = {0.f, 0.f, 0.f, 0.f};

  const int ktmax = (q0 + 15) >> 5;
  for (int kt = 0; kt <= ktmax; kt++) {
    const int k0 = kt * 32;
    f32x4 a0 = (f32x4){0.f, 0.f, 0.f, 0.f}, a1 = (f32x4){0.f, 0.f, 0.f, 0.f};
#pragma unroll
    for (int kd = 0; kd < 4; kd++) {
      bf16x8 kf0 = *(const bf16x8*)(kb + (k0 + li) * 128 + kd * 32 + hi * 8);
      bf16x8 kf1 = *(const bf16x8*)(kb + (k0 + 16 + li) * 128 + kd * 32 + hi * 8);
      a0 = __builtin_amdgcn_mfma_f32_16x16x32_bf16(qf[kd], kf0, a0, 0, 0, 0);
      a1 = __builtin_amdgcn_mfma_f32_16x16x32_bf16(qf[kd], kf1, a1, 0, 0, 0);
    }
    if (k0 + 31 > q0) {
#pragma unroll
      for (int r = 0; r < 4; r++) {
        int q = q0 + hi * 4 + r;
        if (k0 + li > q)      a0[r] = -1e30f;
        if (k0 + 16 + li > q) a1[r] = -1e30f;
      }
    }
    float alpha[4];
#pragma unroll
    for (int r = 0; r < 4; r++) {
      float vmax = fmaxf(a0[r], a1[r]);
#pragma unroll
      for (int off = 1; off < 16; off <<= 1) vmax = fmaxf(vmax, __shfl_xor(vmax, off));
      float mn = fmaxf(m[r], vmax);
      alpha[r] = __expf(m[r] - mn);
      m[r] = mn;
      float p0 = __expf(a0[r] - mn), p1 = __expf(a1[r] - mn);
      a0[r] = p0; a1[r] = p1;
      float sum = p0 + p1;
#pragma unroll
      for (int off = 1; off < 16; off <<= 1) sum += __shfl_xor(sum, off);
      l[r] = l[r] * alpha[r] + sum;
    }
#pragma unroll
    for (int t = 0; t < 8; t++)
#pragma unroll
      for (int r = 0; r < 4; r++) O[t][r] *= alpha[r];

#pragma unroll
    for (int r = 0; r < 4; r++) {
      Pl[w][hi * 4 + r][li]      = f2bf(a0[r]);
      Pl[w][hi * 4 + r][16 + li] = f2bf(a1[r]);
    }
    asm volatile("s_waitcnt lgkmcnt(0)" ::: "memory"); // drain ds_writes
    __builtin_amdgcn_sched_barrier(0);                 // rule #18: pin ordering
    bf16x8 pa = *(const bf16x8*)(&Pl[w][li][hi * 8]);
#pragma unroll
    for (int t = 0; t < 8; t++) {
      bf16x8 vf = *(const bf16x8*)(vb + (t * 16 + li) * 2048 + k0 + hi * 8);
      O[t] = __builtin_amdgcn_mfma_f32_16x16x32_bf16(pa, vf, O[t], 0, 0, 0);
    }
  }

#pragma unroll
  for (int t = 0; t < 8; t++)
#pragma unroll
    for (int r = 0; r < 4; r++) {
      int s = q0 + hi * 4 + r;
      int col = t * 16 + li;
      float g = qg_raw[(long long)(b * 2048 + s) * 4096 + h * 256 + 128 + col];
      float val = (O[t][r] / l[r]) * (1.f / (1.f + __expf(-g)));
      attn_g[(long long)(b * 2048 + s) * 2048 + h * 128 + col] = f2bf(val);
    }
}

// ---------------------------------------------------------------------------
extern "C" void kernel_launch(void* const* d_in, const int* in_sizes, int n_in,
                              void* d_out, int out_size, void* d_ws, size_t ws_size,
                              hipStream_t stream) {
  const float* hs   = (const float*)d_in[0];
  const float* cosb = (const float*)d_in[1];
  const float* sinb = (const float*)d_in[2];
  const float* Wq   = (const float*)d_in[3];
  const float* Wk   = (const float*)d_in[4];
  const float* Wv   = (const float*)d_in[5];
  const float* Wo   = (const float*)d_in[6];
  const float* qnw  = (const float*)d_in[7];
  const float* knw  = (const float*)d_in[8];
  float* out = (float*)d_out;

  const size_t WS_NEEDED = 130023424ull;
  if (ws_size < WS_NEEDED) return;   // fail clean, not a GPU fault

  char* p = (char*)d_ws;
  bf16*  hs_bf  = (bf16*)p;  p += 4096ull * 2048 * 2;   // A: dead after GEMMs
  bf16*  wq_bf  = (bf16*)p;  p += 4096ull * 2048 * 2;   // B: dead after qg GEMM
  bf16*  wkv_bf = (bf16*)p;  p += 1024ull * 2048 * 2;   // C
  bf16*  wo_bf  = (bf16*)p;  p += 2048ull * 2048 * 2;   // E
  float* qg_raw = (float*)p; p += 4096ull * 4096 * 4;   // F: gate read by attn
  float* kv_raw = (float*)p; p += 4096ull * 1024 * 4;   // G: dead after pack/transpose
  bf16* q_pack = (bf16*)hs_bf;                          // over A
  bf16* k_pack = (bf16*)wq_bf;                          // over B
  bf16* vt     = (bf16*)((char*)wq_bf + 2ull * 4 * 2048 * 128 * 2); // over B
  bf16* attn_g = (bf16*)kv_raw;                         // over G

  // 1) converts
  f2b_kernel<<<8192, 256, 0, stream>>>(hs, hs_bf);
  f2b_kernel<<<8192, 256, 0, stream>>>(Wq, wq_bf);
  f2b_kernel<<<1024, 256, 0, stream>>>(Wk, wkv_bf);
  f2b_kernel<<<1024, 256, 0, stream>>>(Wv, wkv_bf + 512 * 2048);
  f2b_kernel<<<4096, 256, 0, stream>>>(Wo, wo_bf);

  // 2) projections
  gemm_bt<<<dim3(32, 32), 256, 0, stream>>>(hs_bf, wq_bf, qg_raw, 4096, 4096, 2048);
  gemm_bt<<<dim3(8, 32), 256, 0, stream>>>(hs_bf, wkv_bf, kv_raw, 4096, 1024, 2048);

  // 3) RMSNorm + RoPE + pack;  4) V transpose
  pack_qk<<<20480, 256, 0, stream>>>(qg_raw, kv_raw, cosb, sinb, qnw, knw, q_pack, k_pack);
  transpose_v<<<dim3(16, 64, 2), 256, 0, stream>>>(kv_raw, vt);

  // 5a) PROBE: R5 swapped-operand attn (output overwritten below)
  attn_probe<<<dim3(16, 32), 256, 0, stream>>>(q_pack, k_pack, vt, qg_raw, attn_g);

  // 5b) AUTHORITATIVE: verified round-4 attn overwrites attn_g
  attn_kernel<<<dim3(32, 32), 256, 0, stream>>>(q_pack, k_pack, vt, qg_raw, attn_g);

  // 6) out = attn_g * Wo^T
  gemm_bt<<<dim3(16, 32), 256, 0, stream>>>(attn_g, wo_bf, out, 4096, 2048, 2048);
}

// Round 12
// 612.438 us; speedup vs baseline: 1.7305x; 1.7305x over previous
//
#include <hip/hip_runtime.h>
#include <stdint.h>

// ---------------------------------------------------------------------------
// Qwen3.5-MoE gated SDPA attention block, MI355X (gfx950)
// R12: identical resubmit of R11 (GPU never acquired). R5 swapped-operand attn
// authoritative; awaiting absmax verdict. B=2 S=2048 HID=2048 H=16 KV=4 D=128
// ---------------------------------------------------------------------------

using bf16 = unsigned short;                                  // raw bf16 bits
typedef __attribute__((ext_vector_type(8)))  short bf16x8;    // MFMA A/B frag
typedef __attribute__((ext_vector_type(4)))  float f32x4;     // 16x16 C/D
typedef __attribute__((ext_vector_type(16))) float f32x16;    // 32x32 C/D

__device__ __forceinline__ unsigned short f2bf(float x) {
  unsigned int u = __float_as_uint(x);
  unsigned int r = u + 0x7fffu + ((u >> 16) & 1u);            // RNE
  return (unsigned short)(r >> 16);
}

__device__ __forceinline__ unsigned int pk2(float a, float b) {
  return (unsigned int)f2bf(a) | ((unsigned int)f2bf(b) << 16);
}

__device__ __forceinline__ void async_copy16(const void* g, void* l) {
  __builtin_amdgcn_global_load_lds(
      (const __attribute__((address_space(1))) void*)g,
      (__attribute__((address_space(3))) void*)l, 16, 0, 0);
}

// ---------------------------------------------------------------------------
// fp32 -> bf16 convert, 4 elems/thread, exact grid
// ---------------------------------------------------------------------------
__global__ void f2b_kernel(const float* __restrict__ in, bf16* __restrict__ out) {
  int i = (blockIdx.x * 256 + threadIdx.x) * 4;
  float4 v = *(const float4*)(in + i);
  ushort4 o;
  o.x = f2bf(v.x); o.y = f2bf(v.y); o.z = f2bf(v.z); o.w = f2bf(v.w);
  *(ushort4*)(out + i) = o;
}

// ---------------------------------------------------------------------------
// C[m][n] = sum_k A[m][k] * B[n][k]   (A MxK bf16, B NxK bf16, C fp32)
// 128x128 tile, BK=32, 4 waves (2x2), m97 structure + XCD swizzle  [verified]
// ---------------------------------------------------------------------------
__global__ __launch_bounds__(256) void gemm_bt(const bf16* __restrict__ A,
                                               const bf16* __restrict__ B,
                                               float* __restrict__ C,
                                               int M, int N, int K) {
  __shared__ __align__(16) bf16 As[128 * 32];
  __shared__ __align__(16) bf16 Bs[128 * 32];
  const int tid = threadIdx.x;
  const int w = tid >> 6, lane = tid & 63;
  const int wr = w >> 1, wc = w & 1;
  const int li = lane & 15, hi = lane >> 4;

  const int nbx = gridDim.x, nwg = nbx * gridDim.y;
  const int orig = blockIdx.y * nbx + blockIdx.x;
  const int tileid = (orig & 7) * (nwg >> 3) + (orig >> 3);
  const int bm = (tileid / nbx) * 128, bn = (tileid % nbx) * 128;

  f32x4 acc[4][4];
#pragma unroll
  for (int m = 0; m < 4; m++)
#pragma unroll
    for (int n = 0; n < 4; n++) acc[m][n] = (f32x4){0.f, 0.f, 0.f, 0.f};

  const int c0 = tid, c1 = tid + 256;
  const bf16* Ab = A + (long long)bm * K;
  const bf16* Bb = B + (long long)bn * K;

  for (int k0 = 0; k0 < K; k0 += 32) {
    async_copy16(Ab + (c0 >> 2) * K + k0 + (c0 & 3) * 8, (char*)As + c0 * 16);
    async_copy16(Ab + (c1 >> 2) * K + k0 + (c1 & 3) * 8, (char*)As + c1 * 16);
    async_copy16(Bb + (c0 >> 2) * K + k0 + (c0 & 3) * 8, (char*)Bs + c0 * 16);
    async_copy16(Bb + (c1 >> 2) * K + k0 + (c1 & 3) * 8, (char*)Bs + c1 * 16);
    __syncthreads();

    bf16x8 af[4], bfv[4];
#pragma unroll
    for (int m = 0; m < 4; m++)
      af[m] = *(const bf16x8*)(As + (wr * 64 + m * 16 + li) * 32 + hi * 8);
#pragma unroll
    for (int n = 0; n < 4; n++)
      bfv[n] = *(const bf16x8*)(Bs + (wc * 64 + n * 16 + li) * 32 + hi * 8);
#pragma unroll
    for (int m = 0; m < 4; m++)
#pragma unroll
      for (int n = 0; n < 4; n++)
        acc[m][n] = __builtin_amdgcn_mfma_f32_16x16x32_bf16(af[m], bfv[n],
                                                            acc[m][n], 0, 0, 0);
    __syncthreads();
  }

#pragma unroll
  for (int m = 0; m < 4; m++)
#pragma unroll
    for (int n = 0; n < 4; n++) {
      int row = bm + wr * 64 + m * 16 + hi * 4;
      int col = bn + wc * 64 + n * 16 + li;
#pragma unroll
      for (int r = 0; r < 4; r++) C[(long long)(row + r) * N + col] = acc[m][n][r];
    }
}

// ---------------------------------------------------------------------------
// RMSNorm + RoPE + pack to bf16 (one wave per (token, head-row))  [verified]
// ---------------------------------------------------------------------------
__global__ __launch_bounds__(256) void pack_qk(
    const float* __restrict__ qg_raw, const float* __restrict__ kv_raw,
    const float* __restrict__ cosb, const float* __restrict__ sinb,
    const float* __restrict__ qnw, const float* __restrict__ knw,
    bf16* __restrict__ q_pack, bf16* __restrict__ k_pack) {
  int rowid = blockIdx.x * 4 + (threadIdx.x >> 6);
  int lane = threadIdx.x & 63;
  int token = rowid / 20, r = rowid % 20;
  int b = token >> 11, s = token & 2047;
  const float* src; const float* wn; bf16* dst; float scale;
  if (r < 16) {
    src = qg_raw + (long long)token * 4096 + r * 256;
    wn = qnw;
    dst = q_pack + ((long long)(b * 16 + r) * 2048 + s) * 128;
    scale = 0.08838834764831845f;                      // D^-0.5 folded into q
  } else {
    int kv = r - 16;
    src = kv_raw + (long long)token * 1024 + kv * 128;
    wn = knw;
    dst = k_pack + ((long long)(b * 4 + kv) * 2048 + s) * 128;
    scale = 1.0f;
  }
  float x0 = src[lane], x1 = src[lane + 64];
  float ss = x0 * x0 + x1 * x1;
#pragma unroll
  for (int off = 32; off > 0; off >>= 1) ss += __shfl_xor(ss, off);
  float inv = rsqrtf(ss * (1.0f / 128.0f) + 1e-6f);
  float n0 = x0 * inv * (1.f + wn[lane]);
  float n1 = x1 * inv * (1.f + wn[lane + 64]);
  const float* cp = cosb + (long long)(b * 2048 + s) * 128;
  const float* sp = sinb + (long long)(b * 2048 + s) * 128;
  dst[lane]      = f2bf((n0 * cp[lane]      - n1 * sp[lane])      * scale);
  dst[lane + 64] = f2bf((n1 * cp[lane + 64] + n0 * sp[lane + 64]) * scale);
}

// ---------------------------------------------------------------------------
// V transpose: kv_raw[token][512+c] (fp32) -> vt[b][c][s] (bf16)  [verified]
// ---------------------------------------------------------------------------
__global__ __launch_bounds__(256) void transpose_v(const float* __restrict__ kv_raw,
                                                   bf16* __restrict__ vt) {
  __shared__ float tile[32][33];
  int b = blockIdx.z;
  int c0 = blockIdx.x * 32;
  int s0 = blockIdx.y * 32;
  int tx = threadIdx.x & 31, ty = threadIdx.x >> 5;
#pragma unroll
  for (int i = 0; i < 32; i += 8)
    tile[ty + i][tx] = kv_raw[(long long)(b * 2048 + s0 + ty + i) * 1024 + 512 + c0 + tx];
  __syncthreads();
#pragma unroll
  for (int i = 0; i < 32; i += 8)
    vt[(long long)(b * 512 + c0 + ty + i) * 2048 + s0 + tx] = f2bf(tile[tx][ty + i]);
}

// ---------------------------------------------------------------------------
// AUTHORITATIVE attn (promoted R5): swapped-operand flash attention.
//   S^T[k][q] = sum_d K[k][d] Q[q][d]   via mfma_32x32x16 (A=K, B=Q)
//   O^T[c][q] = sum_k V[k][c] P[k][q]   via mfma_32x32x16 (A=V^T, B=P)
// Lane owns ONE q = lane&31; softmax state scalar per lane; no LDS/barriers.
// q_pack carries 1/sqrt(D).  Defer-max THR=8 (T13).  Ran clean in R10 bisect
// at ~228us (vs 467us for the 16x16 LDS-round-trip version).
// ---------------------------------------------------------------------------
__global__ __launch_bounds__(256) void attn_kernel(
    const bf16* __restrict__ qp, const bf16* __restrict__ kp,
    const bf16* __restrict__ vt, const float* __restrict__ qg_raw,
    bf16* __restrict__ attn_g) {
  const int w = threadIdx.x >> 6, lane = threadIdx.x & 63;
  const int l31 = lane & 31, hi2 = lane >> 5;
  const int bh = blockIdx.y, b = bh >> 4, h = bh & 15, kv = h >> 2;
  const int qtile = (gridDim.x - 1) - blockIdx.x;       // heavy tiles first
  const int q0w = qtile * 128 + w * 32;
  const int q = q0w + l31;

  const bf16* qb = qp + ((long long)(b * 16 + h) * 2048 + q0w) * 128;
  const bf16* kb = kp + (long long)(b * 4 + kv) * 2048 * 128;
  const bf16* vb = vt + (long long)(b * 4 + kv) * 128 * 2048;

  bf16x8 qf[8];
#pragma unroll
  for (int d = 0; d < 8; d++)
    qf[d] = *(const bf16x8*)(qb + l31 * 128 + d * 16 + hi2 * 8);

  f32x16 O[4];
#pragma unroll
  for (int ct = 0; ct < 4; ct++)
#pragma unroll
    for (int i = 0; i < 16; i++) O[ct][i] = 0.f;

  float mval = -1e30f, lsum = 0.f;
  const int ktmax = q0w >> 5;

  bf16x8 kf[8];
#pragma unroll
  for (int d = 0; d < 8; d++)
    kf[d] = *(const bf16x8*)(kb + l31 * 128 + d * 16 + hi2 * 8);

  for (int kt = 0; kt <= ktmax; kt++) {
    const int k0 = kt * 32;

    f32x16 s;
#pragma unroll
    for (int i = 0; i < 16; i++) s[i] = 0.f;
#pragma unroll
    for (int d = 0; d < 8; d++)
      s = __builtin_amdgcn_mfma_f32_32x32x16_bf16(kf[d], qf[d], s, 0, 0, 0);

    const int k0n = (kt < ktmax) ? (k0 + 32) : k0;
#pragma unroll
    for (int d = 0; d < 8; d++)
      kf[d] = *(const bf16x8*)(kb + (k0n + l31) * 128 + d * 16 + hi2 * 8);

    bf16x8 vf[8];
#pragma unroll
    for (int ct = 0; ct < 4; ct++)
#pragma unroll
      for (int kc = 0; kc < 2; kc++)
        vf[ct * 2 + kc] =
            *(const bf16x8*)(vb + (ct * 32 + l31) * 2048 + k0 + kc * 16 + hi2 * 8);

    if (k0 + 31 > q0w) {
#pragma unroll
      for (int r = 0; r < 16; r++) {
        int kk = k0 + (r & 3) + 8 * (r >> 2) + 4 * hi2;
        if (kk > q) s[r] = -1e30f;
      }
    }

    float pm = s[0];
#pragma unroll
    for (int r = 1; r < 16; r++) pm = fmaxf(pm, s[r]);
    pm = fmaxf(pm, __shfl_xor(pm, 32));

    int keep = __all(pm <= mval + 8.0f);                // T13 defer-max
    float mn = mval, alpha = 1.f;
    if (!keep) {
      mn = fmaxf(mval, pm);
      alpha = __expf(mval - mn);
      mval = mn;
    }
    float sum = 0.f;
#pragma unroll
    for (int r = 0; r < 16; r++) { s[r] = __expf(s[r] - mn); sum += s[r]; }
    sum += __shfl_xor(sum, 32);
    if (keep) {
      lsum += sum;
    } else {
      lsum = lsum * alpha + sum;
#pragma unroll
      for (int ct = 0; ct < 4; ct++)
#pragma unroll
        for (int i = 0; i < 16; i++) O[ct][i] *= alpha;
    }

    bf16x8 pf[2];
#pragma unroll
    for (int kc = 0; kc < 2; kc++) {
      unsigned int wA = pk2(s[8 * kc + 0], s[8 * kc + 1]);
      unsigned int wB = pk2(s[8 * kc + 2], s[8 * kc + 3]);
      unsigned int wC = pk2(s[8 * kc + 4], s[8 * kc + 5]);
      unsigned int wD = pk2(s[8 * kc + 6], s[8 * kc + 7]);
      unsigned int xA = (unsigned int)__shfl_xor((int)wA, 32);
      unsigned int xB = (unsigned int)__shfl_xor((int)wB, 32);
      unsigned int xC = (unsigned int)__shfl_xor((int)wC, 32);
      unsigned int xD = (unsigned int)__shfl_xor((int)wD, 32);
      union { unsigned int u[4]; bf16x8 v; } pu;
      pu.u[0] = hi2 ? xC : wA;
      pu.u[1] = hi2 ? xD : wB;
      pu.u[2] = hi2 ? wC : xA;
      pu.u[3] = hi2 ? wD : xB;
      pf[kc] = pu.v;
    }

#pragma unroll
    for (int ct = 0; ct < 4; ct++) {
      O[ct] = __builtin_amdgcn_mfma_f32_32x32x16_bf16(vf[ct * 2 + 0], pf[0], O[ct], 0, 0, 0);
      O[ct] = __builtin_amdgcn_mfma_f32_32x32x16_bf16(vf[ct * 2 + 1], pf[1], O[ct], 0, 0, 0);
    }
  }

  const float linv = 1.f / lsum;
  const long long tok = (long long)(b * 2048 + q);
#pragma unroll
  for (int ct = 0; ct < 4; ct++)
#pragma unroll
    for (int r = 0; r < 16; r++) {
      int c = ct * 32 + (r & 3) + 8 * (r >> 2) + 4 * hi2;
      float g = qg_raw[tok * 4096 + h * 256 + 128 + c];
      float val = O[ct][r] * linv * (1.f / (1.f + __expf(-g)));
      attn_g[tok * 2048 + h * 128 + c] = f2bf(val);
    }
}

// ---------------------------------------------------------------------------
extern "C" void kernel_launch(void* const* d_in, const int* in_sizes, int n_in,
                              void* d_out, int out_size, void* d_ws, size_t ws_size,
                              hipStream_t stream) {
  const float* hs   = (const float*)d_in[0];
  const float* cosb = (const float*)d_in[1];
  const float* sinb = (const float*)d_in[2];
  const float* Wq   = (const float*)d_in[3];
  const float* Wk   = (const float*)d_in[4];
  const float* Wv   = (const float*)d_in[5];
  const float* Wo   = (const float*)d_in[6];
  const float* qnw  = (const float*)d_in[7];
  const float* knw  = (const float*)d_in[8];
  float* out = (float*)d_out;

  const size_t WS_NEEDED = 130023424ull;
  if (ws_size < WS_NEEDED) return;   // fail clean, not a GPU fault

  char* p = (char*)d_ws;
  bf16*  hs_bf  = (bf16*)p;  p += 4096ull * 2048 * 2;   // A: dead after GEMMs
  bf16*  wq_bf  = (bf16*)p;  p += 4096ull * 2048 * 2;   // B: dead after qg GEMM
  bf16*  wkv_bf = (bf16*)p;  p += 1024ull * 2048 * 2;   // C
  bf16*  wo_bf  = (bf16*)p;  p += 2048ull * 2048 * 2;   // E
  float* qg_raw = (float*)p; p += 4096ull * 4096 * 4;   // F: gate read by attn
  float* kv_raw = (float*)p; p += 4096ull * 1024 * 4;   // G: dead after pack/transpose
  bf16* q_pack = (bf16*)hs_bf;                          // over A
  bf16* k_pack = (bf16*)wq_bf;                          // over B
  bf16* vt     = (bf16*)((char*)wq_bf + 2ull * 4 * 2048 * 128 * 2); // over B
  bf16* attn_g = (bf16*)kv_raw;                         // over G

  // 1) converts
  f2b_kernel<<<8192, 256, 0, stream>>>(hs, hs_bf);
  f2b_kernel<<<8192, 256, 0, stream>>>(Wq, wq_bf);
  f2b_kernel<<<1024, 256, 0, stream>>>(Wk, wkv_bf);
  f2b_kernel<<<1024, 256, 0, stream>>>(Wv, wkv_bf + 512 * 2048);
  f2b_kernel<<<4096, 256, 0, stream>>>(Wo, wo_bf);

  // 2) projections
  gemm_bt<<<dim3(32, 32), 256, 0, stream>>>(hs_bf, wq_bf, qg_raw, 4096, 4096, 2048);
  gemm_bt<<<dim3(8, 32), 256, 0, stream>>>(hs_bf, wkv_bf, kv_raw, 4096, 1024, 2048);

  // 3) RMSNorm + RoPE + pack;  4) V transpose
  pack_qk<<<20480, 256, 0, stream>>>(qg_raw, kv_raw, cosb, sinb, qnw, knw, q_pack, k_pack);
  transpose_v<<<dim3(16, 64, 2), 256, 0, stream>>>(kv_raw, vt);

  // 5) flash attention + sigmoid gating (swapped-operand, 128 q-rows/block)
  attn_kernel<<<dim3(16, 32), 256, 0, stream>>>(q_pack, k_pack, vt, qg_raw, attn_g);

  // 6) out = attn_g * Wo^T
  gemm_bt<<<dim3(16, 32), 256, 0, stream>>>(attn_g, wo_bf, out, 4096, 2048, 2048);
}

// Round 13
// 557.367 us; speedup vs baseline: 1.9015x; 1.0988x over previous
//
#include <hip/hip_runtime.h>
#include <stdint.h>

// ---------------------------------------------------------------------------
// Qwen3.5-MoE gated SDPA attention block, MI355X (gfx950)
// R13: attn K/V^T now cooperatively LDS-staged (gload_lds + source-pre-swizzle,
// double-buffered, shared by 4 waves) to kill the 32-line/load fragment
// gathers (R12: 245us @ MfmaUtil 5.6%, all pipes idle = transaction-bound).
// transpose_v emits V^T in 8KB k-tile-contiguous layout for coalesced staging.
// B=2 S=2048 HID=2048 H=16 KV=4 D=128
// ---------------------------------------------------------------------------

using bf16 = unsigned short;                                  // raw bf16 bits
typedef __attribute__((ext_vector_type(8)))  short bf16x8;    // MFMA A/B frag
typedef __attribute__((ext_vector_type(4)))  float f32x4;     // 16x16 C/D
typedef __attribute__((ext_vector_type(16))) float f32x16;    // 32x32 C/D

__device__ __forceinline__ unsigned short f2bf(float x) {
  unsigned int u = __float_as_uint(x);
  unsigned int r = u + 0x7fffu + ((u >> 16) & 1u);            // RNE
  return (unsigned short)(r >> 16);
}

__device__ __forceinline__ unsigned int pk2(float a, float b) {
  return (unsigned int)f2bf(a) | ((unsigned int)f2bf(b) << 16);
}

__device__ __forceinline__ void async_copy16(const void* g, void* l) {
  __builtin_amdgcn_global_load_lds(
      (const __attribute__((address_space(1))) void*)g,
      (__attribute__((address_space(3))) void*)l, 16, 0, 0);
}

// ---------------------------------------------------------------------------
// fp32 -> bf16 convert, 4 elems/thread, exact grid
// ---------------------------------------------------------------------------
__global__ void f2b_kernel(const float* __restrict__ in, bf16* __restrict__ out) {
  int i = (blockIdx.x * 256 + threadIdx.x) * 4;
  float4 v = *(const float4*)(in + i);
  ushort4 o;
  o.x = f2bf(v.x); o.y = f2bf(v.y); o.z = f2bf(v.z); o.w = f2bf(v.w);
  *(ushort4*)(out + i) = o;
}

// ---------------------------------------------------------------------------
// C[m][n] = sum_k A[m][k] * B[n][k]   (A MxK bf16, B NxK bf16, C fp32)
// 128x128 tile, BK=32, 4 waves (2x2), m97 structure + XCD swizzle  [verified]
// ---------------------------------------------------------------------------
__global__ __launch_bounds__(256) void gemm_bt(const bf16* __restrict__ A,
                                               const bf16* __restrict__ B,
                                               float* __restrict__ C,
                                               int M, int N, int K) {
  __shared__ __align__(16) bf16 As[128 * 32];
  __shared__ __align__(16) bf16 Bs[128 * 32];
  const int tid = threadIdx.x;
  const int w = tid >> 6, lane = tid & 63;
  const int wr = w >> 1, wc = w & 1;
  const int li = lane & 15, hi = lane >> 4;

  const int nbx = gridDim.x, nwg = nbx * gridDim.y;
  const int orig = blockIdx.y * nbx + blockIdx.x;
  const int tileid = (orig & 7) * (nwg >> 3) + (orig >> 3);
  const int bm = (tileid / nbx) * 128, bn = (tileid % nbx) * 128;

  f32x4 acc[4][4];
#pragma unroll
  for (int m = 0; m < 4; m++)
#pragma unroll
    for (int n = 0; n < 4; n++) acc[m][n] = (f32x4){0.f, 0.f, 0.f, 0.f};

  const int c0 = tid, c1 = tid + 256;
  const bf16* Ab = A + (long long)bm * K;
  const bf16* Bb = B + (long long)bn * K;

  for (int k0 = 0; k0 < K; k0 += 32) {
    async_copy16(Ab + (c0 >> 2) * K + k0 + (c0 & 3) * 8, (char*)As + c0 * 16);
    async_copy16(Ab + (c1 >> 2) * K + k0 + (c1 & 3) * 8, (char*)As + c1 * 16);
    async_copy16(Bb + (c0 >> 2) * K + k0 + (c0 & 3) * 8, (char*)Bs + c0 * 16);
    async_copy16(Bb + (c1 >> 2) * K + k0 + (c1 & 3) * 8, (char*)Bs + c1 * 16);
    __syncthreads();

    bf16x8 af[4], bfv[4];
#pragma unroll
    for (int m = 0; m < 4; m++)
      af[m] = *(const bf16x8*)(As + (wr * 64 + m * 16 + li) * 32 + hi * 8);
#pragma unroll
    for (int n = 0; n < 4; n++)
      bfv[n] = *(const bf16x8*)(Bs + (wc * 64 + n * 16 + li) * 32 + hi * 8);
#pragma unroll
    for (int m = 0; m < 4; m++)
#pragma unroll
      for (int n = 0; n < 4; n++)
        acc[m][n] = __builtin_amdgcn_mfma_f32_16x16x32_bf16(af[m], bfv[n],
                                                            acc[m][n], 0, 0, 0);
    __syncthreads();
  }

#pragma unroll
  for (int m = 0; m < 4; m++)
#pragma unroll
    for (int n = 0; n < 4; n++) {
      int row = bm + wr * 64 + m * 16 + hi * 4;
      int col = bn + wc * 64 + n * 16 + li;
#pragma unroll
      for (int r = 0; r < 4; r++) C[(long long)(row + r) * N + col] = acc[m][n][r];
    }
}

// ---------------------------------------------------------------------------
// RMSNorm + RoPE + pack to bf16 (one wave per (token, head-row))  [verified]
// ---------------------------------------------------------------------------
__global__ __launch_bounds__(256) void pack_qk(
    const float* __restrict__ qg_raw, const float* __restrict__ kv_raw,
    const float* __restrict__ cosb, const float* __restrict__ sinb,
    const float* __restrict__ qnw, const float* __restrict__ knw,
    bf16* __restrict__ q_pack, bf16* __restrict__ k_pack) {
  int rowid = blockIdx.x * 4 + (threadIdx.x >> 6);
  int lane = threadIdx.x & 63;
  int token = rowid / 20, r = rowid % 20;
  int b = token >> 11, s = token & 2047;
  const float* src; const float* wn; bf16* dst; float scale;
  if (r < 16) {
    src = qg_raw + (long long)token * 4096 + r * 256;
    wn = qnw;
    dst = q_pack + ((long long)(b * 16 + r) * 2048 + s) * 128;
    scale = 0.08838834764831845f;                      // D^-0.5 folded into q
  } else {
    int kv = r - 16;
    src = kv_raw + (long long)token * 1024 + kv * 128;
    wn = knw;
    dst = k_pack + ((long long)(b * 4 + kv) * 2048 + s) * 128;
    scale = 1.0f;
  }
  float x0 = src[lane], x1 = src[lane + 64];
  float ss = x0 * x0 + x1 * x1;
#pragma unroll
  for (int off = 32; off > 0; off >>= 1) ss += __shfl_xor(ss, off);
  float inv = rsqrtf(ss * (1.0f / 128.0f) + 1e-6f);
  float n0 = x0 * inv * (1.f + wn[lane]);
  float n1 = x1 * inv * (1.f + wn[lane + 64]);
  const float* cp = cosb + (long long)(b * 2048 + s) * 128;
  const float* sp = sinb + (long long)(b * 2048 + s) * 128;
  dst[lane]      = f2bf((n0 * cp[lane]      - n1 * sp[lane])      * scale);
  dst[lane + 64] = f2bf((n1 * cp[lane + 64] + n0 * sp[lane + 64]) * scale);
}

// ---------------------------------------------------------------------------
// V transpose -> k-tile-contiguous V^T: vt[((b*4+kv)*64 + kt)*4096 + c*32 + st]
// Each (kt) tile is 128 rows (c) x 32 cols (s) bf16 = 8KB contiguous.
// ---------------------------------------------------------------------------
__global__ __launch_bounds__(256) void transpose_v(const float* __restrict__ kv_raw,
                                                   bf16* __restrict__ vt) {
  __shared__ float tile[32][33];
  int b = blockIdx.z;
  int c0 = blockIdx.x * 32;     // global v-col 0..480
  int s0 = blockIdx.y * 32;
  int tx = threadIdx.x & 31, ty = threadIdx.x >> 5;
#pragma unroll
  for (int i = 0; i < 32; i += 8)
    tile[ty + i][tx] = kv_raw[(long long)(b * 2048 + s0 + ty + i) * 1024 + 512 + c0 + tx];
  __syncthreads();
  int kt = s0 >> 5;
#pragma unroll
  for (int i = 0; i < 32; i += 8) {
    int cg = c0 + ty + i;                 // global col in [0,512)
    int kvh = cg >> 7, c = cg & 127;
    vt[((long long)(b * 4 + kvh) * 64 + kt) * 4096 + c * 32 + tx] = f2bf(tile[tx][ty + i]);
  }
}

// ---------------------------------------------------------------------------
// AUTHORITATIVE attn: swapped-operand flash attention (verified R12 algebra)
// + cooperative double-buffered LDS staging of K and V^T tiles.
//   S^T[k][q] = mfma_32x32x16(A=K, B=Q);  O^T[c][q] = mfma(A=V^T, B=P)
// K tile: 32x128 bf16 (8KB, 256B rows), granule-XOR gd^(r&15).
// V tile: 128x32 bf16 (8KB, 64B rows),  granule-XOR gv^((c>>1)&3).
// Staging: gload_lds with inverse-swizzled per-lane global source (rule #21).
// All 4 waves iterate to block ktmax = 4*qtile+3 (extra tiles fully masked).
// ---------------------------------------------------------------------------
__global__ __launch_bounds__(256) void attn_kernel(
    const bf16* __restrict__ qp, const bf16* __restrict__ kp,
    const bf16* __restrict__ vt, const float* __restrict__ qg_raw,
    bf16* __restrict__ attn_g) {
  __shared__ __align__(16) char Ks[2][8192];
  __shared__ __align__(16) char Vs[2][8192];
  const int w = threadIdx.x >> 6, lane = threadIdx.x & 63;
  const int l31 = lane & 31, hi2 = lane >> 5;
  const int bh = blockIdx.y, b = bh >> 4, h = bh & 15, kv = h >> 2;
  const int qtile = (gridDim.x - 1) - blockIdx.x;       // heavy tiles first
  const int q0w = qtile * 128 + w * 32;
  const int q = q0w + l31;

  const bf16* qb = qp + ((long long)(b * 16 + h) * 2048 + q0w) * 128;
  const char* kbb = (const char*)(kp + (long long)(b * 4 + kv) * 2048 * 128);
  const char* vbb = (const char*)(vt + (long long)(b * 4 + kv) * 64 * 4096);

  // staging offsets: this thread stages granules p = (w*2+i)*64 + lane
  int ksrco[2], vsrco[2], dsto[2];
#pragma unroll
  for (int i = 0; i < 2; i++) {
    int p = (w * 2 + i) * 64 + lane;
    int rk = p >> 4, gk = p & 15;                       // K: 16 granules/row
    ksrco[i] = rk * 256 + ((gk ^ (rk & 15)) << 4);      // inverse-swizzled src
    int rv = p >> 2, gv = p & 3;                        // V: 4 granules/row
    vsrco[i] = rv * 64 + ((gv ^ ((rv >> 1) & 3)) << 4);
    dsto[i] = p << 4;                                   // = wave-uniform + lane*16
  }

  // Q fragments: B-operand, col=q=lane&31 (one-time gather, acceptable)
  bf16x8 qf[8];
#pragma unroll
  for (int d = 0; d < 8; d++)
    qf[d] = *(const bf16x8*)(qb + l31 * 128 + d * 16 + hi2 * 8);

  f32x16 O[4];
#pragma unroll
  for (int ct = 0; ct < 4; ct++)
#pragma unroll
    for (int i = 0; i < 16; i++) O[ct][i] = 0.f;

  float mval = -1e30f, lsum = 0.f;
  const int ktmaxb = qtile * 4 + 3;                     // block-common trip count

  // prologue: stage tile 0
#pragma unroll
  for (int i = 0; i < 2; i++) {
    async_copy16(kbb + ksrco[i], &Ks[0][dsto[i]]);
    async_copy16(vbb + vsrco[i], &Vs[0][dsto[i]]);
  }
  __syncthreads();

  for (int kt = 0; kt <= ktmaxb; kt++) {
    const int bi = kt & 1;
    const int k0 = kt * 32;

    if (kt < ktmaxb) {                                  // stage next tile
      const char* ksrc = kbb + (long long)(kt + 1) * 8192;
      const char* vsrc = vbb + (long long)(kt + 1) * 8192;
#pragma unroll
      for (int i = 0; i < 2; i++) {
        async_copy16(ksrc + ksrco[i], &Ks[bi ^ 1][dsto[i]]);
        async_copy16(vsrc + vsrco[i], &Vs[bi ^ 1][dsto[i]]);
      }
    }

    // fragments from LDS (swizzled reads)
    bf16x8 kf[8];
#pragma unroll
    for (int d = 0; d < 8; d++)
      kf[d] = *(const bf16x8*)&Ks[bi][l31 * 256 + (((d * 2 + hi2) ^ (l31 & 15)) << 4)];
    bf16x8 vf[8];
#pragma unroll
    for (int ct = 0; ct < 4; ct++)
#pragma unroll
      for (int kc = 0; kc < 2; kc++)
        vf[ct * 2 + kc] = *(const bf16x8*)
            &Vs[bi][(ct * 32 + l31) * 64 + (((kc * 2 + hi2) ^ ((l31 >> 1) & 3)) << 4)];

    // S^T = K * Q^T
    f32x16 s;
#pragma unroll
    for (int i = 0; i < 16; i++) s[i] = 0.f;
#pragma unroll
    for (int d = 0; d < 8; d++)
      s = __builtin_amdgcn_mfma_f32_32x32x16_bf16(kf[d], qf[d], s, 0, 0, 0);

    // causal mask: lane's held S rows are k = k0 + (r&3)+8*(r>>2)+4*hi2
    if (k0 + 31 > q0w) {
#pragma unroll
      for (int r = 0; r < 16; r++) {
        int kk = k0 + (r & 3) + 8 * (r >> 2) + 4 * hi2;
        if (kk > q) s[r] = -1e30f;
      }
    }

    // online softmax (lane-local row; combine with lane^32 partner)
    float pm = s[0];
#pragma unroll
    for (int r = 1; r < 16; r++) pm = fmaxf(pm, s[r]);
    pm = fmaxf(pm, __shfl_xor(pm, 32));

    int keep = __all(pm <= mval + 8.0f);                // T13 defer-max
    float mn = mval, alpha = 1.f;
    if (!keep) {
      mn = fmaxf(mval, pm);
      alpha = __expf(mval - mn);
      mval = mn;
    }
    float sum = 0.f;
#pragma unroll
    for (int r = 0; r < 16; r++) { s[r] = __expf(s[r] - mn); sum += s[r]; }
    sum += __shfl_xor(sum, 32);
    if (keep) {
      lsum += sum;
    } else {
      lsum = lsum * alpha + sum;
#pragma unroll
      for (int ct = 0; ct < 4; ct++)
#pragma unroll
        for (int i = 0; i < 16; i++) O[ct][i] *= alpha;
    }

    // pack P to bf16 B-fragments: half-swap with lane^32 partner
    bf16x8 pf[2];
#pragma unroll
    for (int kc = 0; kc < 2; kc++) {
      unsigned int wA = pk2(s[8 * kc + 0], s[8 * kc + 1]);
      unsigned int wB = pk2(s[8 * kc + 2], s[8 * kc + 3]);
      unsigned int wC = pk2(s[8 * kc + 4], s[8 * kc + 5]);
      unsigned int wD = pk2(s[8 * kc + 6], s[8 * kc + 7]);
      unsigned int xA = (unsigned int)__shfl_xor((int)wA, 32);
      unsigned int xB = (unsigned int)__shfl_xor((int)wB, 32);
      unsigned int xC = (unsigned int)__shfl_xor((int)wC, 32);
      unsigned int xD = (unsigned int)__shfl_xor((int)wD, 32);
      union { unsigned int u[4]; bf16x8 v; } pu;
      pu.u[0] = hi2 ? xC : wA;
      pu.u[1] = hi2 ? xD : wB;
      pu.u[2] = hi2 ? wC : xA;
      pu.u[3] = hi2 ? wD : xB;
      pf[kc] = pu.v;
    }

    // O^T += V^T * P
#pragma unroll
    for (int ct = 0; ct < 4; ct++) {
      O[ct] = __builtin_amdgcn_mfma_f32_32x32x16_bf16(vf[ct * 2 + 0], pf[0], O[ct], 0, 0, 0);
      O[ct] = __builtin_amdgcn_mfma_f32_32x32x16_bf16(vf[ct * 2 + 1], pf[1], O[ct], 0, 0, 0);
    }

    __syncthreads();   // drains vmcnt (next-tile staging) + lgkm; buffer flip
  }

  // epilogue: /l, sigmoid(gate), store.  Lane holds O^T[c-set][q].
  const float linv = 1.f / lsum;
  const long long tok = (long long)(b * 2048 + q);
#pragma unroll
  for (int ct = 0; ct < 4; ct++)
#pragma unroll
    for (int r = 0; r < 16; r++) {
      int c = ct * 32 + (r & 3) + 8 * (r >> 2) + 4 * hi2;
      float g = qg_raw[tok * 4096 + h * 256 + 128 + c];
      float val = O[ct][r] * linv * (1.f / (1.f + __expf(-g)));
      attn_g[tok * 2048 + h * 128 + c] = f2bf(val);
    }
}

// ---------------------------------------------------------------------------
extern "C" void kernel_launch(void* const* d_in, const int* in_sizes, int n_in,
                              void* d_out, int out_size, void* d_ws, size_t ws_size,
                              hipStream_t stream) {
  const float* hs   = (const float*)d_in[0];
  const float* cosb = (const float*)d_in[1];
  const float* sinb = (const float*)d_in[2];
  const float* Wq   = (const float*)d_in[3];
  const float* Wk   = (const float*)d_in[4];
  const float* Wv   = (const float*)d_in[5];
  const float* Wo   = (const float*)d_in[6];
  const float* qnw  = (const float*)d_in[7];
  const float* knw  = (const float*)d_in[8];
  float* out = (float*)d_out;

  const size_t WS_NEEDED = 130023424ull;
  if (ws_size < WS_NEEDED) return;   // fail clean, not a GPU fault

  char* p = (char*)d_ws;
  bf16*  hs_bf  = (bf16*)p;  p += 4096ull * 2048 * 2;   // A: dead after GEMMs
  bf16*  wq_bf  = (bf16*)p;  p += 4096ull * 2048 * 2;   // B: dead after qg GEMM
  bf16*  wkv_bf = (bf16*)p;  p += 1024ull * 2048 * 2;   // C
  bf16*  wo_bf  = (bf16*)p;  p += 2048ull * 2048 * 2;   // E
  float* qg_raw = (float*)p; p += 4096ull * 4096 * 4;   // F: gate read by attn
  float* kv_raw = (float*)p; p += 4096ull * 1024 * 4;   // G: dead after pack/transpose
  bf16* q_pack = (bf16*)hs_bf;                          // over A
  bf16* k_pack = (bf16*)wq_bf;                          // over B
  bf16* vt     = (bf16*)((char*)wq_bf + 2ull * 4 * 2048 * 128 * 2); // over B
  bf16* attn_g = (bf16*)kv_raw;                         // over G

  // 1) converts
  f2b_kernel<<<8192, 256, 0, stream>>>(hs, hs_bf);
  f2b_kernel<<<8192, 256, 0, stream>>>(Wq, wq_bf);
  f2b_kernel<<<1024, 256, 0, stream>>>(Wk, wkv_bf);
  f2b_kernel<<<1024, 256, 0, stream>>>(Wv, wkv_bf + 512 * 2048);
  f2b_kernel<<<4096, 256, 0, stream>>>(Wo, wo_bf);

  // 2) projections
  gemm_bt<<<dim3(32, 32), 256, 0, stream>>>(hs_bf, wq_bf, qg_raw, 4096, 4096, 2048);
  gemm_bt<<<dim3(8, 32), 256, 0, stream>>>(hs_bf, wkv_bf, kv_raw, 4096, 1024, 2048);

  // 3) RMSNorm + RoPE + pack;  4) V transpose (k-tile-contiguous layout)
  pack_qk<<<20480, 256, 0, stream>>>(qg_raw, kv_raw, cosb, sinb, qnw, knw, q_pack, k_pack);
  transpose_v<<<dim3(16, 64, 2), 256, 0, stream>>>(kv_raw, vt);

  // 5) flash attention + sigmoid gating (swapped-operand + LDS staging)
  attn_kernel<<<dim3(16, 32), 256, 0, stream>>>(q_pack, k_pack, vt, qg_raw, attn_g);

  // 6) out = attn_g * Wo^T
  gemm_bt<<<dim3(16, 32), 256, 0, stream>>>(attn_g, wo_bf, out, 4096, 2048, 2048);
}